// Round 3
// baseline (281.483 us; speedup 1.0000x reference)
//
#include <hip/hip_runtime.h>
#include <stdint.h>

#define N_ROIS 6144
#define NCLS 20
#define NC1 21
#define TOPK 615          // ceil(0.1 * 6144)
#define IOU_TH 0.25f
#define BUCKETS 8192      // 2^13: (int)(s*8192) is exact & monotone for s in [0,1)
#define CAND 1024
#define KEEP_CAP 256
#define EMAX 1024

// ---------------------------------------------------------------------------
// K_A: per-class fused {preds column, exact top-K select, greedy NMS}.
// One 1024-thread block per class (inactive classes exit).
//  - histogram scores into 8192 buckets; hierarchical (wave-reduce + t0 walk)
//    search from the top finds the threshold bucket tb and need = K - |above|.
//  - compact candidates (bucket >= tb) as 64-bit keys (~score_bits<<32)|idx:
//    ascending key == (desc score, asc idx) == jnp stable argsort order.
//  - demote all but the 'need' smallest keys inside tb -> exact top-K SET.
//  - greedy NMS without any sort: repeatedly block-argmin over alive keys
//    (= pop highest score, stable ties), suppress alive cands with
//    iou(row_selected) >= thr (selected kills itself via diag 1.0).
//    ~4-6 iterations for this data. Emits (roi, score_bits) kept list.
// ---------------------------------------------------------------------------
__global__ __launch_bounds__(1024) void k_select_nms(
    const float* __restrict__ pc, const float* __restrict__ pd,
    const int* __restrict__ labels, const float* __restrict__ iou,
    int* __restrict__ kept_cnt, int2* __restrict__ kept_pairs) {
  const int c = blockIdx.x;
  if (labels[c] <= 0) return;               // block-uniform: safe early exit
  __shared__ int hist[BUCKETS];             // 32 KB
  __shared__ unsigned long long key[CAND];  // 8 KB
  __shared__ int chunk[1024];
  __shared__ int wsum[16];
  __shared__ unsigned long long wmin[16];
  __shared__ unsigned long long s_win;
  __shared__ int s_tb, s_need, s_cnt, s_kcnt;
  const int tid = threadIdx.x;

  for (int i = tid; i < BUCKETS; i += 1024) hist[i] = 0;
  key[tid] = ~0ull;
  if (tid == 0) { s_cnt = 0; s_kcnt = 0; }
  __syncthreads();

  // fused preds: score = pc[n, c+1] * pd[n, c+1]  (column gather, L2-resident)
  float sc[6];
  #pragma unroll
  for (int k = 0; k < 6; ++k) {
    int n = tid + (k << 10);                // 6144 = 6 * 1024
    int off = n * NC1 + (c + 1);
    float s = pc[off] * pd[off];
    sc[k] = s;
    int b = (int)(s * (float)BUCKETS);
    b = min(max(b, 0), BUCKETS - 1);
    atomicAdd(&hist[b], 1);
  }
  __syncthreads();

  // threshold bucket: thread t owns reversed-bucket range [t*8, t*8+8)
  int own = 0;
  #pragma unroll
  for (int k = 0; k < 8; ++k) own += hist[BUCKETS - 1 - (tid * 8 + k)];
  chunk[tid] = own;
  int r = own;
  #pragma unroll
  for (int m = 1; m < 64; m <<= 1) r += __shfl_xor(r, m, 64);
  if ((tid & 63) == 0) wsum[tid >> 6] = r;
  __syncthreads();

  if (tid == 0) {                           // ~16+64+8 LDS reads, serial
    int cum = 0, w = 0;
    for (; w < 15; ++w) { if (cum + wsum[w] >= TOPK) break; cum += wsum[w]; }
    int t = w << 6;
    for (;; ++t) { if (cum + chunk[t] >= TOPK) break; cum += chunk[t]; }
    int tb = 0, need = TOPK - cum;
    #pragma unroll
    for (int k = 0; k < 8; ++k) {
      int b = BUCKETS - 1 - (t * 8 + k);
      int h = hist[b];
      if (cum + h >= TOPK) { tb = b; need = TOPK - cum; break; }
      cum += h;
    }
    s_tb = tb; s_need = need;
  }
  __syncthreads();
  const int tb = s_tb, need = s_need;

  // compact candidates with bucket >= tb
  #pragma unroll
  for (int k = 0; k < 6; ++k) {
    float s = sc[k];
    int b = (int)(s * (float)BUCKETS);
    b = min(max(b, 0), BUCKETS - 1);
    if (b >= tb) {
      int pos = atomicAdd(&s_cnt, 1);
      if (pos < CAND) {
        unsigned bits = __float_as_uint(s);
        key[pos] = ((unsigned long long)(~bits) << 32) | (unsigned)(tid + (k << 10));
      }
    }
  }
  __syncthreads();

  // exact boundary: inside tb keep only the 'need' smallest keys
  const int cnt = min(s_cnt, CAND);
  {
    unsigned long long mykey = key[tid];
    bool demote = false;
    if (tid < cnt && mykey != ~0ull) {
      unsigned bits = ~(unsigned)(mykey >> 32);
      float s = __uint_as_float(bits);
      int b = (int)(s * (float)BUCKETS);
      b = min(max(b, 0), BUCKETS - 1);
      if (b == tb) {                        // only ~1-5 threads enter
        int rank = 0;
        for (int j = 0; j < cnt; ++j) {
          unsigned long long kj = key[j];
          if (kj < mykey) {
            unsigned bj = ~(unsigned)(kj >> 32);
            float sj = __uint_as_float(bj);
            int bb = (int)(sj * (float)BUCKETS);
            bb = min(max(bb, 0), BUCKETS - 1);
            if (bb == tb) ++rank;           // keys unique (idx embedded)
          }
        }
        demote = (rank >= need);
      }
    }
    __syncthreads();
    if (demote) key[tid] = ~0ull;
    __syncthreads();
  }

  // greedy NMS: pop block-min key (= max score, stable), suppress by IoU row
  while (true) {
    unsigned long long v = key[tid];
    #pragma unroll
    for (int m = 1; m < 64; m <<= 1) {      // wave min-reduce (u64 via 2x32)
      unsigned lo = __shfl_xor((unsigned)v, m, 64);
      unsigned hi = __shfl_xor((unsigned)(v >> 32), m, 64);
      unsigned long long u = ((unsigned long long)hi << 32) | lo;
      if (u < v) v = u;
    }
    if ((tid & 63) == 0) wmin[tid >> 6] = v;
    __syncthreads();
    if (tid == 0) {
      unsigned long long m2 = wmin[0];
      #pragma unroll
      for (int w = 1; w < 16; ++w) if (wmin[w] < m2) m2 = wmin[w];
      s_win = m2;
    }
    __syncthreads();
    const unsigned long long win = s_win;
    if (win == ~0ull) break;                // all dead -> done
    const int bi = (int)(win & 0xffffffffu);
    if (key[tid] == win) {                  // unique owner records the keep
      int p = s_kcnt;
      if (p < KEEP_CAP)
        kept_pairs[c * KEEP_CAP + p] = make_int2(bi, (int)(~(unsigned)(win >> 32)));
      s_kcnt = p + 1;
    }
    if (key[tid] != ~0ull) {                // suppress (selected: diag iou = 1)
      int n = (int)(key[tid] & 0xffffffffu);
      if (iou[(size_t)bi * N_ROIS + n] >= IOU_TH) key[tid] = ~0ull;
    }
    __syncthreads();
  }
  if (tid == 0) kept_cnt[c] = min(s_kcnt, KEEP_CAP);
}

// ---------------------------------------------------------------------------
// K_B: fused {cross-class competition, GT table, per-roi max/argmax, outputs}.
// Every block rebuilds the tiny (~50 entry) GT table in LDS from the kept
// lists (broadcast loads, L2-hit), resolves per-roi winners with the
// reference's sequential-overwrite semantics (strict >, earliest class on
// tie), then scans GT columns via symmetric ROWS (coalesced across n).
// Tie-break (max v, min roi id) == jnp.argmax first occurrence.
// ---------------------------------------------------------------------------
__global__ __launch_bounds__(256) void k_out(
    const float* __restrict__ iou, const int* __restrict__ labels,
    const int* __restrict__ kept_cnt, const int2* __restrict__ kept_pairs,
    float* __restrict__ out) {
  __shared__ int   e_n[EMAX];
  __shared__ float e_s[EMAX];
  __shared__ short e_c[EMAX];
  __shared__ unsigned char e_ok[EMAX];
  __shared__ int s_E;
  const int tid = threadIdx.x;
  if (tid == 0) s_E = 0;
  __syncthreads();
  if (tid < NCLS && labels[tid] > 0) {      // inactive classes never written
    int cnt = min(kept_cnt[tid], KEEP_CAP);
    for (int t = 0; t < cnt; ++t) {
      int2 pr = kept_pairs[tid * KEEP_CAP + t];
      int p = atomicAdd(&s_E, 1);
      if (p < EMAX) { e_n[p] = pr.x; e_s[p] = __int_as_float(pr.y); e_c[p] = (short)tid; }
    }
  }
  __syncthreads();
  const int E = min(s_E, EMAX);
  // dedup/competition: entry survives iff no entry on same roi with
  // (higher score) or (equal score and earlier class)  [order-independent]
  for (int i = tid; i < E; i += 256) {
    int n = e_n[i]; float s = e_s[i]; int cc = e_c[i];
    bool ok = true;
    for (int j = 0; j < E; ++j) {
      if (j == i || e_n[j] != n) continue;
      float sj = e_s[j];
      if (sj > s || (sj == s && e_c[j] < cc)) { ok = false; break; }
    }
    e_ok[i] = ok ? 1 : 0;
  }
  __syncthreads();

  const int n = blockIdx.x * 256 + tid;
  float maxv = -1.0f;                       // non-GT cols are -1 in reference
  int mslot = -1, mn = N_ROIS;
  for (int j = 0; j < E; ++j) {
    if (!e_ok[j]) continue;
    int nj = e_n[j];
    float v = iou[(size_t)nj * N_ROIS + n]; // symmetric: row read, coalesced
    if (v > maxv || (v == maxv && nj < mn)) { maxv = v; mn = nj; mslot = j; }
  }
  float lw; int pl;
  if (mslot >= 0) { lw = e_s[mslot]; pl = (int)e_c[mslot] + 1; }
  else { lw = -1.0f; pl = 0; }              // E==0: ref gives maxv=-1, w=-1
  bool ignore = (maxv == 0.0f);
  bool bg = (maxv < IOU_TH) && !ignore;
  float row[NC1];
  #pragma unroll
  for (int k = 0; k < NC1; ++k) row[k] = 0.0f;
  if (ignore) lw = 0.0f;
  else if (bg) row[0] = 1.0f;
  else row[pl] = 1.0f;
  #pragma unroll
  for (int k = 0; k < NC1; ++k) out[(size_t)n * NC1 + k] = row[k];
  out[(size_t)N_ROIS * NC1 + n] = maxv;
  out[(size_t)N_ROIS * NC1 + N_ROIS + n] = lw;
}

// ---------------------------------------------------------------------------
extern "C" void kernel_launch(void* const* d_in, const int* in_sizes, int n_in,
                              void* d_out, int out_size, void* d_ws, size_t ws_size,
                              hipStream_t stream) {
  const float* pc     = (const float*)d_in[0];   // predict_cls (N, 21)
  const float* pd     = (const float*)d_in[1];   // predict_det (N, 21)
  // d_in[2] = rois: unused by the reference result
  const int*   labels = (const int*)d_in[3];     // (20,)
  const float* iou    = (const float*)d_in[4];   // (N, N)
  float* out = (float*)d_out;

  int2* kept_pairs = (int2*)d_ws;                              // 20*256*8 B
  int*  kept_cnt   = (int*)((char*)d_ws + NCLS * KEEP_CAP * 8);

  k_select_nms<<<NCLS, 1024, 0, stream>>>(pc, pd, labels, iou, kept_cnt, kept_pairs);
  k_out<<<N_ROIS / 256, 256, 0, stream>>>(iou, labels, kept_cnt, kept_pairs, out);
}

// Round 4
// 275.600 us; speedup vs baseline: 1.0213x; 1.0213x over previous
//
#include <hip/hip_runtime.h>
#include <stdint.h>

#define N_ROIS 6144
#define NCLS 20
#define NC1 21
#define TOPK 615          // ceil(0.1 * 6144)
#define IOU_TH 0.25f
#define BUCKETS 8192      // 2^13: (int)(s*8192) exact & monotone for s in [0,1)
#define CAND 1024
#define KEEP_CAP 128
#define EMAX 640

// ---------------------------------------------------------------------------
// K0: coalesced transpose-multiply. Block b handles rows [b*256, b*256+256).
// Reads 256*21 contiguous floats of pc,pd (coalesced), products into LDS,
// writes 20 columns out coalesced: preds_t[c*N + n]. Stride-21 LDS reads are
// conflict-free (21 coprime with 32; 2 lanes/bank is free on CDNA4).
// ---------------------------------------------------------------------------
__global__ __launch_bounds__(256) void k_prep(const float* __restrict__ pc,
                                              const float* __restrict__ pd,
                                              float* __restrict__ preds_t) {
  __shared__ float tile[256 * NC1];
  const int tid = threadIdx.x;
  const int base = blockIdx.x * 256;
  const size_t g = (size_t)base * NC1;
  for (int i = tid; i < 256 * NC1; i += 256) tile[i] = pc[g + i] * pd[g + i];
  __syncthreads();
  #pragma unroll
  for (int c = 0; c < NCLS; ++c)
    preds_t[(size_t)c * N_ROIS + base + tid] = tile[tid * NC1 + (c + 1)];
}

// ---------------------------------------------------------------------------
// K1: per-class {exact top-K select, greedy NMS}. One 512-thread block/class.
// Column read is CONTIGUOUS (preds_t), L2-warm. Bucket histogram -> threshold
// bucket tb + need; compact keys (~score_bits<<32)|idx (ascending == desc
// score, asc idx == jnp stable argsort); demote all but 'need' smallest in tb
// -> exact top-K set. NMS = repeated block-min pop (~5 iters for this data),
// suppression via one scattered IoU-row probe per alive candidate.
// ---------------------------------------------------------------------------
__global__ __launch_bounds__(512) void k_select_nms(
    const float* __restrict__ preds_t, const int* __restrict__ labels,
    const float* __restrict__ iou,
    int* __restrict__ kept_cnt, int2* __restrict__ kept_pairs) {
  const int c = blockIdx.x;
  if (labels[c] <= 0) return;               // block-uniform: safe early exit
  __shared__ int hist[BUCKETS];             // 32 KB
  __shared__ unsigned long long key[CAND];  // 8 KB
  __shared__ int chunk[512];
  __shared__ int wsum[8];
  __shared__ unsigned long long wmin[8];
  __shared__ int s_tb, s_need, s_cnt;
  const int tid = threadIdx.x;
  const int lane = tid & 63, wid = tid >> 6;

  for (int i = tid; i < BUCKETS; i += 512) hist[i] = 0;
  for (int i = tid; i < CAND; i += 512) key[i] = ~0ull;
  if (tid == 0) s_cnt = 0;
  __syncthreads();

  // coalesced column read: 12 scores/thread, histogram
  float sc[12];
  #pragma unroll
  for (int k = 0; k < 12; ++k) {
    int n = tid + (k << 9);                 // 6144 = 12 * 512
    float s = preds_t[(size_t)c * N_ROIS + n];
    sc[k] = s;
    int b = (int)(s * (float)BUCKETS);
    b = min(max(b, 0), BUCKETS - 1);
    atomicAdd(&hist[b], 1);
  }
  __syncthreads();

  // thread t owns reversed buckets [t*16, t*16+16)
  int own = 0;
  #pragma unroll
  for (int k = 0; k < 16; ++k) own += hist[BUCKETS - 1 - (tid * 16 + k)];
  chunk[tid] = own;
  int r = own;
  #pragma unroll
  for (int m = 1; m < 64; m <<= 1) r += __shfl_xor(r, m, 64);
  if (lane == 0) wsum[wid] = r;
  __syncthreads();

  if (tid == 0) {                           // short serial walk
    int cum = 0, w = 0;
    for (; w < 7; ++w) { if (cum + wsum[w] >= TOPK) break; cum += wsum[w]; }
    int t = w << 6;
    for (;; ++t) { if (cum + chunk[t] >= TOPK) break; cum += chunk[t]; }
    int tb = 0, need = TOPK - cum;
    #pragma unroll
    for (int k = 0; k < 16; ++k) {
      int b = BUCKETS - 1 - (t * 16 + k);
      int h = hist[b];
      if (cum + h >= TOPK) { tb = b; need = TOPK - cum; break; }
      cum += h;
    }
    s_tb = tb; s_need = need;
  }
  __syncthreads();
  const int tb = s_tb, need = s_need;

  // compact candidates with bucket >= tb
  #pragma unroll
  for (int k = 0; k < 12; ++k) {
    float s = sc[k];
    int b = (int)(s * (float)BUCKETS);
    b = min(max(b, 0), BUCKETS - 1);
    if (b >= tb) {
      int pos = atomicAdd(&s_cnt, 1);
      if (pos < CAND) {
        unsigned bits = __float_as_uint(s);
        key[pos] = ((unsigned long long)(~bits) << 32) | (unsigned)(tid + (k << 9));
      }
    }
  }
  __syncthreads();

  // exact boundary: inside tb keep only the 'need' smallest keys
  const int cnt = min(s_cnt, CAND);
  for (int sl = tid; sl < CAND; sl += 512) {
    unsigned long long mykey = key[sl];
    bool demote = false;
    if (sl < cnt && mykey != ~0ull) {
      unsigned bits = ~(unsigned)(mykey >> 32);
      float s = __uint_as_float(bits);
      int b = (int)(s * (float)BUCKETS);
      b = min(max(b, 0), BUCKETS - 1);
      if (b == tb) {                        // ~1-5 threads enter
        int rank = 0;
        for (int j = 0; j < cnt; ++j) {
          unsigned long long kj = key[j];
          if (kj < mykey) {
            unsigned bj = ~(unsigned)(kj >> 32);
            float sj = __uint_as_float(bj);
            int bb = (int)(sj * (float)BUCKETS);
            bb = min(max(bb, 0), BUCKETS - 1);
            if (bb == tb) ++rank;           // keys unique (idx embedded)
          }
        }
        demote = (rank >= need);
      }
    }
    __syncthreads();
    if (demote) key[sl] = ~0ull;
    __syncthreads();
  }

  // greedy NMS: pop block-min key (= max score, stable ties), suppress by row
  int npop = 0;
  while (true) {
    unsigned long long v = key[tid];
    { unsigned long long v2 = key[tid + 512]; if (v2 < v) v = v2; }
    #pragma unroll
    for (int m = 1; m < 64; m <<= 1) {      // wave u64 min via 2x32 shfl
      unsigned lo = __shfl_xor((unsigned)v, m, 64);
      unsigned hi = __shfl_xor((unsigned)(v >> 32), m, 64);
      unsigned long long u = ((unsigned long long)hi << 32) | lo;
      if (u < v) v = u;
    }
    if (lane == 0) wmin[wid] = v;
    __syncthreads();
    unsigned long long win = wmin[0];
    #pragma unroll
    for (int w = 1; w < 8; ++w) if (wmin[w] < win) win = wmin[w];
    if (win == ~0ull) break;                // all dead -> done
    const int bi = (int)(win & 0xffffffffu);
    const float* row = iou + (size_t)bi * N_ROIS;
    for (int sl = tid; sl < CAND; sl += 512) {
      unsigned long long kk = key[sl];
      if (kk == ~0ull) continue;
      if (kk == win && npop < KEEP_CAP)     // unique owner records the keep
        kept_pairs[c * KEEP_CAP + npop] = make_int2(bi, (int)(~(unsigned)(win >> 32)));
      int n = (int)(kk & 0xffffffffu);
      if (row[n] >= IOU_TH) key[sl] = ~0ull; // diag 1.0 kills selected itself
    }
    ++npop;                                 // block-uniform pop ordinal
    __syncthreads();
  }
  if (tid == 0) kept_cnt[c] = min(npop, KEEP_CAP);
}

// ---------------------------------------------------------------------------
// K2: fused {cross-class competition, GT table, per-roi max/argmax, outputs}.
// Each block rebuilds the tiny (~55 entry) GT table in LDS, resolves winners
// with reference semantics (strict >, earliest class on tie), scans GT
// columns via symmetric ROWS (coalesced across n). Tie-break (max v, min roi)
// == jnp.argmax first occurrence.
// ---------------------------------------------------------------------------
__global__ __launch_bounds__(256) void k_out(
    const float* __restrict__ iou, const int* __restrict__ labels,
    const int* __restrict__ kept_cnt, const int2* __restrict__ kept_pairs,
    float* __restrict__ out) {
  __shared__ int   e_n[EMAX];
  __shared__ float e_s[EMAX];
  __shared__ short e_c[EMAX];
  __shared__ unsigned char e_ok[EMAX];
  __shared__ int s_E;
  const int tid = threadIdx.x;
  if (tid == 0) s_E = 0;
  __syncthreads();
  if (tid < NCLS && labels[tid] > 0) {      // inactive classes never written
    int cnt = min(kept_cnt[tid], KEEP_CAP);
    for (int t = 0; t < cnt; ++t) {
      int2 pr = kept_pairs[tid * KEEP_CAP + t];
      int p = atomicAdd(&s_E, 1);
      if (p < EMAX) { e_n[p] = pr.x; e_s[p] = __int_as_float(pr.y); e_c[p] = (short)tid; }
    }
  }
  __syncthreads();
  const int E = min(s_E, EMAX);
  // competition: survive iff no same-roi entry with (higher score) or
  // (equal score and earlier class) — order-independent == sequential ref
  for (int i = tid; i < E; i += 256) {
    int n = e_n[i]; float s = e_s[i]; int cc = e_c[i];
    bool ok = true;
    for (int j = 0; j < E; ++j) {
      if (j == i || e_n[j] != n) continue;
      float sj = e_s[j];
      if (sj > s || (sj == s && e_c[j] < cc)) { ok = false; break; }
    }
    e_ok[i] = ok ? 1 : 0;
  }
  __syncthreads();

  const int n = blockIdx.x * 256 + tid;
  float maxv = -1.0f;                       // non-GT cols are -1 in reference
  int mslot = -1, mn = N_ROIS;
  for (int j = 0; j < E; ++j) {
    if (!e_ok[j]) continue;
    int nj = e_n[j];
    float v = iou[(size_t)nj * N_ROIS + n]; // symmetric: row read, coalesced
    if (v > maxv || (v == maxv && nj < mn)) { maxv = v; mn = nj; mslot = j; }
  }
  float lw; int pl;
  if (mslot >= 0) { lw = e_s[mslot]; pl = (int)e_c[mslot] + 1; }
  else { lw = -1.0f; pl = 0; }              // E==0: ref -> maxv=-1, w=-1
  bool ignore = (maxv == 0.0f);
  bool bg = (maxv < IOU_TH) && !ignore;
  float row[NC1];
  #pragma unroll
  for (int k = 0; k < NC1; ++k) row[k] = 0.0f;
  if (ignore) lw = 0.0f;
  else if (bg) row[0] = 1.0f;
  else row[pl] = 1.0f;
  #pragma unroll
  for (int k = 0; k < NC1; ++k) out[(size_t)n * NC1 + k] = row[k];
  out[(size_t)N_ROIS * NC1 + n] = maxv;
  out[(size_t)N_ROIS * NC1 + N_ROIS + n] = lw;
}

// ---------------------------------------------------------------------------
extern "C" void kernel_launch(void* const* d_in, const int* in_sizes, int n_in,
                              void* d_out, int out_size, void* d_ws, size_t ws_size,
                              hipStream_t stream) {
  const float* pc     = (const float*)d_in[0];   // predict_cls (N, 21)
  const float* pd     = (const float*)d_in[1];   // predict_det (N, 21)
  // d_in[2] = rois: unused by the reference result
  const int*   labels = (const int*)d_in[3];     // (20,)
  const float* iou    = (const float*)d_in[4];   // (N, N)
  float* out = (float*)d_out;

  char* ws = (char*)d_ws;
  float* preds_t  = (float*)ws;                            // 20*6144*4 B
  int2*  kept_pairs = (int2*)(ws + (size_t)NCLS * N_ROIS * 4); // 20*128*8 B
  int*   kept_cnt = (int*)((char*)kept_pairs + NCLS * KEEP_CAP * 8);

  k_prep      <<<N_ROIS / 256, 256, 0, stream>>>(pc, pd, preds_t);
  k_select_nms<<<NCLS, 512, 0, stream>>>(preds_t, labels, iou, kept_cnt, kept_pairs);
  k_out       <<<N_ROIS / 256, 256, 0, stream>>>(iou, labels, kept_cnt, kept_pairs, out);
}

// Round 5
// 274.198 us; speedup vs baseline: 1.0266x; 1.0051x over previous
//
#include <hip/hip_runtime.h>
#include <stdint.h>

#define N_ROIS 6144
#define NCLS 20
#define NC1 21
#define TOPK 615          // ceil(0.1 * 6144)
#define IOU_TH 0.25f
#define BUCKETS 8192      // 2^13: (int)(s*8192) exact & monotone for s in [0,1)
#define CAND 1024
#define KEEP_CAP 128
#define EMAX 640

// ---------------------------------------------------------------------------
// K0: coalesced transpose-multiply. Block b: rows [b*256, b*256+256).
// Coalesced read of pc/pd, product via LDS, coalesced column writes.
// Stride-21 LDS reads: 21 coprime 32 -> <=2 lanes/bank (free on CDNA4).
// ---------------------------------------------------------------------------
__global__ __launch_bounds__(256) void k_prep(const float* __restrict__ pc,
                                              const float* __restrict__ pd,
                                              float* __restrict__ preds_t) {
  __shared__ float tile[256 * NC1];
  const int tid = threadIdx.x;
  const int base = blockIdx.x * 256;
  const size_t g = (size_t)base * NC1;
  for (int i = tid; i < 256 * NC1; i += 256) tile[i] = pc[g + i] * pd[g + i];
  __syncthreads();
  #pragma unroll
  for (int c = 0; c < NCLS; ++c)
    preds_t[(size_t)c * N_ROIS + base + tid] = tile[tid * NC1 + (c + 1)];
}

// ---------------------------------------------------------------------------
// K1: per-class {exact top-K select, greedy NMS}, one 512-thread block/class.
// Threshold bucket found via fully-parallel shfl scan (no serial t0 walk):
// the unique thread with exc < K <= inc walks only its own 16 buckets.
// Then: compact keys (~score_bits<<32)|idx (asc == desc score, asc idx ==
// jnp stable argsort), demote all but 'need' smallest inside tb -> exact
// top-K SET. NMS = repeated block-min pop (~5 iters), suppress via one
// scattered IoU-row probe per alive candidate (diag 1.0 kills selected).
// ---------------------------------------------------------------------------
__global__ __launch_bounds__(512) void k_select_nms(
    const float* __restrict__ preds_t, const int* __restrict__ labels,
    const float* __restrict__ iou,
    int* __restrict__ kept_cnt, int2* __restrict__ kept_pairs) {
  const int c = blockIdx.x;
  if (labels[c] <= 0) return;               // block-uniform: safe early exit
  __shared__ int hist[BUCKETS];             // 32 KB
  __shared__ unsigned long long key[CAND];  // 8 KB
  __shared__ int wsum[8];
  __shared__ unsigned long long wmin[8];
  __shared__ int s_tb, s_need, s_cnt;
  const int tid = threadIdx.x;
  const int lane = tid & 63, wid = tid >> 6;

  for (int i = tid; i < BUCKETS; i += 512) hist[i] = 0;
  key[tid] = ~0ull; key[tid + 512] = ~0ull;
  if (tid == 0) s_cnt = 0;
  __syncthreads();

  // coalesced column read (L2-warm from k_prep): 12 scores/thread + histogram
  float sc[12];
  #pragma unroll
  for (int k = 0; k < 12; ++k) {
    int n = tid + (k << 9);                 // 6144 = 12 * 512
    float s = preds_t[(size_t)c * N_ROIS + n];
    sc[k] = s;
    int b = (int)(s * (float)BUCKETS);
    b = min(max(b, 0), BUCKETS - 1);
    atomicAdd(&hist[b], 1);
  }
  __syncthreads();

  // thread t owns reversed buckets [t*16, t*16+16); parallel inclusive scan
  int own = 0;
  #pragma unroll
  for (int k = 0; k < 16; ++k) own += hist[BUCKETS - 1 - (tid * 16 + k)];
  int inc = own;
  #pragma unroll
  for (int m = 1; m < 64; m <<= 1) {
    int v = __shfl_up(inc, m, 64);
    if (lane >= m) inc += v;
  }
  if (lane == 63) wsum[wid] = inc;
  __syncthreads();
  #pragma unroll
  for (int w = 0; w < 8; ++w) inc += (w < wid) ? wsum[w] : 0;
  int exc = inc - own;
  if (exc < TOPK && inc >= TOPK) {          // unique crossing thread
    int cum = exc, tb = 0, need = TOPK - cum;
    #pragma unroll
    for (int k = 0; k < 16; ++k) {
      int b = BUCKETS - 1 - (tid * 16 + k);
      int h = hist[b];
      if (cum + h >= TOPK) { tb = b; need = TOPK - cum; break; }
      cum += h;
    }
    s_tb = tb; s_need = need;
  }
  __syncthreads();
  const int tb = s_tb, need = s_need;

  // compact candidates with bucket >= tb
  #pragma unroll
  for (int k = 0; k < 12; ++k) {
    float s = sc[k];
    int b = (int)(s * (float)BUCKETS);
    b = min(max(b, 0), BUCKETS - 1);
    if (b >= tb) {
      int pos = atomicAdd(&s_cnt, 1);
      if (pos < CAND) {
        unsigned bits = __float_as_uint(s);
        key[pos] = ((unsigned long long)(~bits) << 32) | (unsigned)(tid + (k << 9));
      }
    }
  }
  __syncthreads();

  // exact boundary: inside tb keep only the 'need' smallest keys
  const int cnt = min(s_cnt, CAND);
  for (int sl = tid; sl < CAND; sl += 512) {
    unsigned long long mykey = key[sl];
    bool demote = false;
    if (sl < cnt && mykey != ~0ull) {
      unsigned bits = ~(unsigned)(mykey >> 32);
      float s = __uint_as_float(bits);
      int b = (int)(s * (float)BUCKETS);
      b = min(max(b, 0), BUCKETS - 1);
      if (b == tb) {                        // ~1-5 threads enter
        int rank = 0;
        for (int j = 0; j < cnt; ++j) {
          unsigned long long kj = key[j];
          if (kj < mykey) {
            unsigned bj = ~(unsigned)(kj >> 32);
            float sj = __uint_as_float(bj);
            int bb = (int)(sj * (float)BUCKETS);
            bb = min(max(bb, 0), BUCKETS - 1);
            if (bb == tb) ++rank;           // keys unique (idx embedded)
          }
        }
        demote = (rank >= need);
      }
    }
    __syncthreads();
    if (demote) key[sl] = ~0ull;
    __syncthreads();
  }

  // greedy NMS: pop block-min key (= max score, stable ties), suppress by row
  int npop = 0;
  while (true) {
    unsigned long long v = key[tid];
    { unsigned long long v2 = key[tid + 512]; if (v2 < v) v = v2; }
    #pragma unroll
    for (int m = 1; m < 64; m <<= 1) {      // wave u64 min via 2x32 shfl
      unsigned lo = __shfl_xor((unsigned)v, m, 64);
      unsigned hi = __shfl_xor((unsigned)(v >> 32), m, 64);
      unsigned long long u = ((unsigned long long)hi << 32) | lo;
      if (u < v) v = u;
    }
    if (lane == 0) wmin[wid] = v;
    __syncthreads();
    unsigned long long win = wmin[0];
    #pragma unroll
    for (int w = 1; w < 8; ++w) if (wmin[w] < win) win = wmin[w];
    if (win == ~0ull) break;                // all dead -> done
    const int bi = (int)(win & 0xffffffffu);
    const float* row = iou + (size_t)bi * N_ROIS;
    for (int sl = tid; sl < CAND; sl += 512) {
      unsigned long long kk = key[sl];
      if (kk == ~0ull) continue;
      if (kk == win && npop < KEEP_CAP)     // unique owner records the keep
        kept_pairs[c * KEEP_CAP + npop] = make_int2(bi, (int)(~(unsigned)(win >> 32)));
      int n = (int)(kk & 0xffffffffu);
      if (row[n] >= IOU_TH) key[sl] = ~0ull;
    }
    ++npop;                                 // block-uniform pop ordinal
    __syncthreads();
  }
  if (tid == 0) kept_cnt[c] = min(npop, KEEP_CAP);
}

// ---------------------------------------------------------------------------
// K2: build the global deduped GT table ONCE (1 block). Competition ==
// reference sequential overwrite: survive iff no same-roi entry with higher
// score, or equal score and earlier class (order-independent). Packed entry:
// .x = n | (cls<<16), .y = score bits. Output order arbitrary (downstream
// comparator is order-independent).
// ---------------------------------------------------------------------------
__global__ __launch_bounds__(256) void k_table(
    const int* __restrict__ labels, const int* __restrict__ kept_cnt,
    const int2* __restrict__ kept_pairs,
    int2* __restrict__ gt_tab, int* __restrict__ gt_cnt) {
  __shared__ int   e_n[EMAX];
  __shared__ float e_s[EMAX];
  __shared__ short e_c[EMAX];
  __shared__ int2  dense[EMAX];
  __shared__ int s_E, s_live;
  const int tid = threadIdx.x;
  if (tid == 0) { s_E = 0; s_live = 0; }
  __syncthreads();
  if (tid < NCLS * 8) {                     // 8 loader threads per class
    int c = tid >> 3;
    if (labels[c] > 0) {                    // inactive: kept_cnt never written
      int cnt = min(kept_cnt[c], KEEP_CAP);
      for (int i = tid & 7; i < cnt; i += 8) {
        int2 pr = kept_pairs[c * KEEP_CAP + i];
        int p = atomicAdd(&s_E, 1);
        if (p < EMAX) { e_n[p] = pr.x; e_s[p] = __int_as_float(pr.y); e_c[p] = (short)c; }
      }
    }
  }
  __syncthreads();
  const int E = min(s_E, EMAX);
  for (int i = tid; i < E; i += 256) {
    int n = e_n[i]; float s = e_s[i]; int cc = e_c[i];
    bool ok = true;
    for (int j = 0; j < E; ++j) {
      if (j == i || e_n[j] != n) continue;
      float sj = e_s[j];
      if (sj > s || (sj == s && e_c[j] < cc)) { ok = false; break; }
    }
    if (ok) {
      int p = atomicAdd(&s_live, 1);
      dense[p] = make_int2(n | (cc << 16), __float_as_int(s));
    }
  }
  __syncthreads();
  const int L = min(s_live, EMAX);
  for (int i = tid; i < L; i += 256) gt_tab[i] = dense[i];
  if (tid == 0) *gt_cnt = L;
}

// ---------------------------------------------------------------------------
// K3: outputs. Load dense GT table (~52 entries) into LDS in one parallel
// step; branch-free unroll-4 scan of GT columns via symmetric ROWS
// (coalesced across n). Tie-break (max v, min roi) == jnp.argmax first
// occurrence. E==0: maxv=-1 -> bg path, lw=-1 (matches reference).
// ---------------------------------------------------------------------------
__global__ __launch_bounds__(256) void k_out(
    const float* __restrict__ iou, const int2* __restrict__ gt_tab,
    const int* __restrict__ gt_cnt, float* __restrict__ out) {
  __shared__ int   e_nj[EMAX];
  __shared__ int   e_cls[EMAX];
  __shared__ float e_sc[EMAX];
  const int tid = threadIdx.x;
  const int E = *gt_cnt;                    // L2-resident scalar broadcast
  for (int i = tid; i < E; i += 256) {
    int2 v = gt_tab[i];
    e_nj[i] = v.x & 0xFFFF; e_cls[i] = v.x >> 16; e_sc[i] = __int_as_float(v.y);
  }
  __syncthreads();

  const int n = blockIdx.x * 256 + tid;
  float maxv = -1.0f;                       // non-GT cols are -1 in reference
  int mslot = -1, mn = N_ROIS;
  #pragma unroll 4
  for (int j = 0; j < E; ++j) {
    int nj = e_nj[j];
    float v = iou[(size_t)nj * N_ROIS + n]; // symmetric: row read, coalesced
    if (v > maxv || (v == maxv && nj < mn)) { maxv = v; mn = nj; mslot = j; }
  }
  float lw; int pl;
  if (mslot >= 0) { lw = e_sc[mslot]; pl = e_cls[mslot] + 1; }
  else { lw = -1.0f; pl = 0; }
  bool ignore = (maxv == 0.0f);
  bool bg = (maxv < IOU_TH) && !ignore;
  float row[NC1];
  #pragma unroll
  for (int k = 0; k < NC1; ++k) row[k] = 0.0f;
  if (ignore) lw = 0.0f;
  else if (bg) row[0] = 1.0f;
  else row[pl] = 1.0f;
  #pragma unroll
  for (int k = 0; k < NC1; ++k) out[(size_t)n * NC1 + k] = row[k];
  out[(size_t)N_ROIS * NC1 + n] = maxv;
  out[(size_t)N_ROIS * NC1 + N_ROIS + n] = lw;
}

// ---------------------------------------------------------------------------
extern "C" void kernel_launch(void* const* d_in, const int* in_sizes, int n_in,
                              void* d_out, int out_size, void* d_ws, size_t ws_size,
                              hipStream_t stream) {
  const float* pc     = (const float*)d_in[0];   // predict_cls (N, 21)
  const float* pd     = (const float*)d_in[1];   // predict_det (N, 21)
  // d_in[2] = rois: unused by the reference result
  const int*   labels = (const int*)d_in[3];     // (20,)
  const float* iou    = (const float*)d_in[4];   // (N, N)
  float* out = (float*)d_out;

  char* ws = (char*)d_ws;
  size_t off = 0;
  float* preds_t    = (float*)(ws + off); off += (size_t)NCLS * N_ROIS * 4;
  int2*  kept_pairs = (int2*)(ws + off);  off += (size_t)NCLS * KEEP_CAP * 8;
  int*   kept_cnt   = (int*)(ws + off);   off += 128;          // 80 B + pad
  int2*  gt_tab     = (int2*)(ws + off);  off += (size_t)EMAX * 8;
  int*   gt_cnt     = (int*)(ws + off);   off += 4;

  k_prep      <<<N_ROIS / 256, 256, 0, stream>>>(pc, pd, preds_t);
  k_select_nms<<<NCLS, 512, 0, stream>>>(preds_t, labels, iou, kept_cnt, kept_pairs);
  k_table     <<<1, 256, 0, stream>>>(labels, kept_cnt, kept_pairs, gt_tab, gt_cnt);
  k_out       <<<N_ROIS / 256, 256, 0, stream>>>(iou, gt_tab, gt_cnt, out);
}